// Round 8
// baseline (430.176 us; speedup 1.0000x reference)
//
#include <hip/hip_runtime.h>

#define SEQ    256
#define BATCHN 2048
#define NIN    64
#define H      128
#define NOUT   64
#define TOUT   128
#define BT     16     // batch rows per block -> 128 blocks (chain-bound; grid width is irrelevant)
#define ASTR   200    // LDS A-row stride in halfs (192 + 8 pad)
#define TCH    16     // decoder steps buffered before a coalesced flush
#define LOG2E  1.44269504f

using half8 = _Float16 __attribute__((ext_vector_type(8)));
using f32x4 = float    __attribute__((ext_vector_type(4)));

__device__ __forceinline__ float ex2(float v) { return __builtin_amdgcn_exp2f(v); }

__device__ __forceinline__ half8 ldfrag8(const float* __restrict__ p, float s) {
    half8 r;
#pragma unroll
    for (int e = 0; e < 8; ++e) r[e] = (_Float16)(p[e] * s);
    return r;
}

// Fused seq2seq, round 8 (= round-7 package with __builtin_amdgcn_exp2f).
// Gates arrive PRE-SCALED: i,f,o by log2e; g by 2*log2e  ->  exp2 directly.
// sigma(i)*tanh(g) = (B-1)/((1+A)(1+B)), A=2^-i', B=2^g'  (1 rcp instead of 2).
__global__ __launch_bounds__(512, 1) void seq2seq_fused(
    const float* __restrict__ x,
    const float* __restrict__ eWih, const float* __restrict__ eWhh, const float* __restrict__ eb,
    const float* __restrict__ dWih, const float* __restrict__ dWhh, const float* __restrict__ db,
    const float* __restrict__ oW,   const float* __restrict__ obv,
    float* __restrict__ out)
{
    __shared__ __align__(16) _Float16 als[2][BT][ASTR];  // [b][k], k: 0..63 = x/y, 64..191 = h
    __shared__ __align__(16) _Float16 ybuf[TCH][BT][68]; // staged decoder outputs

    const int tid  = threadIdx.x;
    const int lane = tid & 63;
    const int w    = tid >> 6;
    const int jl   = lane & 15;
    const int lg   = lane >> 4;
    const int b0   = blockIdx.x * BT;

    // ---------------- encoder weights -> resident VGPR fragments (pre-scaled) ----------------
    half8 wf[4][6];
    float bq[4];
#pragma unroll
    for (int q = 0; q < 4; ++q) {
        const float sq = (q == 2) ? 2.f * LOG2E : LOG2E;
        const int j = q * H + w * 16 + jl;
#pragma unroll
        for (int kc = 0; kc < 2; ++kc)
            wf[q][kc] = ldfrag8(eWih + j * NIN + kc * 32 + lg * 8, sq);
#pragma unroll
        for (int kc = 2; kc < 6; ++kc)
            wf[q][kc] = ldfrag8(eWhh + j * H + (kc - 2) * 32 + lg * 8, sq);
        bq[q] = eb[j] * sq;
    }

    float c[4] = {0.f, 0.f, 0.f, 0.f};  // cell state (natural units), rows 4*lg+r, col jl

    for (int i = tid; i < 2 * BT * ASTR; i += 512) ((_Float16*)als)[i] = (_Float16)0.f;
    __syncthreads();
    const int xi = tid >> 5, xn = (tid & 31) * 2;
    {
        const float2 xv = *(const float2*)(x + (b0 + xi) * NIN + xn);
        als[0][xi][xn]     = (_Float16)xv.x;
        als[0][xi][xn + 1] = (_Float16)xv.y;
    }
    __syncthreads();

    // one LSTM step body: reads als[cur], writes h and next-x into als[cur^1]
    auto step_body = [&](int cur, float2 xv, bool wx) {
        const int nxt = cur ^ 1;

        half8 af[6];
#pragma unroll
        for (int kc = 0; kc < 6; ++kc)
            af[kc] = *(const half8*)&als[cur][jl][kc * 32 + lg * 8];

        f32x4 ac[4];
#pragma unroll
        for (int q = 0; q < 4; ++q) {
            f32x4 aA = {bq[q], bq[q], bq[q], bq[q]};
            f32x4 aB = {0.f, 0.f, 0.f, 0.f};
#pragma unroll
            for (int kc = 0; kc < 3; ++kc) {
                aA = __builtin_amdgcn_mfma_f32_16x16x32_f16(af[kc],     wf[q][kc],     aA, 0, 0, 0);
                aB = __builtin_amdgcn_mfma_f32_16x16x32_f16(af[kc + 3], wf[q][kc + 3], aB, 0, 0, 0);
            }
            ac[q] = aA + aB;
        }

        // phase-structured elementwise (ILP across r); 5 exp2 + 3 rcp per (row,col)
        float A0[4], B0[4], F0[4], D0[4], E2[4], itv[4], hv[4];
#pragma unroll
        for (int r = 0; r < 4; ++r) A0[r] = ex2(-ac[0][r]);
#pragma unroll
        for (int r = 0; r < 4; ++r) B0[r] = ex2(fminf(ac[2][r], 44.f));
#pragma unroll
        for (int r = 0; r < 4; ++r) F0[r] = ex2(-ac[1][r]);
#pragma unroll
        for (int r = 0; r < 4; ++r) D0[r] = ex2(-ac[3][r]);
#pragma unroll
        for (int r = 0; r < 4; ++r)
            itv[r] = (B0[r] - 1.f) * __builtin_amdgcn_rcpf((1.f + A0[r]) * (1.f + B0[r]));
#pragma unroll
        for (int r = 0; r < 4; ++r)
            c[r] = __builtin_amdgcn_rcpf(1.f + F0[r]) * c[r] + itv[r];
#pragma unroll
        for (int r = 0; r < 4; ++r) E2[r] = ex2(fminf(2.8853901f * c[r], 44.f));
#pragma unroll
        for (int r = 0; r < 4; ++r)
            hv[r] = (E2[r] - 1.f) * __builtin_amdgcn_rcpf((1.f + D0[r]) * (1.f + E2[r]));
#pragma unroll
        for (int r = 0; r < 4; ++r)
            als[nxt][lg * 4 + r][NIN + w * 16 + jl] = (_Float16)hv[r];

        if (wx) {
            als[nxt][xi][xn]     = (_Float16)xv.x;
            als[nxt][xi][xn + 1] = (_Float16)xv.y;
        }
        __syncthreads();
    };

    // ---------------- encoder: 256 steps, x loads batched x4 ----------------
    for (int tg = 0; tg < SEQ; tg += 4) {
        float2 xq0 = make_float2(0.f, 0.f), xq1 = xq0, xq2 = xq0, xq3 = xq0;
        // issue 4 future x loads up-front; drained (at latest) at this group's first barrier
        if (tg + 1 < SEQ) xq0 = *(const float2*)(x + ((size_t)(tg + 1) * BATCHN + b0 + xi) * NIN + xn);
        if (tg + 2 < SEQ) xq1 = *(const float2*)(x + ((size_t)(tg + 2) * BATCHN + b0 + xi) * NIN + xn);
        if (tg + 3 < SEQ) xq2 = *(const float2*)(x + ((size_t)(tg + 3) * BATCHN + b0 + xi) * NIN + xn);
        if (tg + 4 < SEQ) xq3 = *(const float2*)(x + ((size_t)(tg + 4) * BATCHN + b0 + xi) * NIN + xn);
        step_body(0, xq0, true);
        step_body(1, xq1, true);
        step_body(0, xq2, true);
        step_body(1, xq3, true);   // last group writes zeros -> decoder x0
    }

    // ---------------- decoder weights (reuse registers, pre-scaled) ----------------
#pragma unroll
    for (int q = 0; q < 4; ++q) {
        const float sq = (q == 2) ? 2.f * LOG2E : LOG2E;
        const int j = q * H + w * 16 + jl;
#pragma unroll
        for (int kc = 0; kc < 2; ++kc)
            wf[q][kc] = ldfrag8(dWih + j * NIN + kc * 32 + lg * 8, sq);
#pragma unroll
        for (int kc = 2; kc < 6; ++kc)
            wf[q][kc] = ldfrag8(dWhh + j * H + (kc - 2) * 32 + lg * 8, sq);
        bq[q] = db[j] * sq;
    }
    half8 of[4];
    float oB = 0.f;
    if (w < 4) {  // waves 0..3 own the y-GEMM (natural units, no scaling)
        const int j = w * 16 + jl;
#pragma unroll
        for (int kc = 0; kc < 4; ++kc)
            of[kc] = ldfrag8(oW + j * H + kc * 32 + lg * 8, 1.f);
        oB = obv[j];
    }

    // ---------------- decoder: 128 steps, 2 barriers/step ----------------
    for (int s = 0; s < TOUT; ++s) {
        const int cur = s & 1, nxt = cur ^ 1;

        step_body(cur, make_float2(0.f, 0.f), false);  // gate GEMM + cell update; h -> als[nxt]

        if (w < 4) {
            half8 hf[4];
#pragma unroll
            for (int kc = 0; kc < 4; ++kc)
                hf[kc] = *(const half8*)&als[nxt][jl][NIN + kc * 32 + lg * 8];
            f32x4 ya = {oB, oB, oB, oB};
#pragma unroll
            for (int kc = 0; kc < 4; ++kc)
                ya = __builtin_amdgcn_mfma_f32_16x16x32_f16(hf[kc], of[kc], ya, 0, 0, 0);
            const int j = w * 16 + jl;
            const int tt = s & (TCH - 1);
#pragma unroll
            for (int r = 0; r < 4; ++r) {
                const int row = lg * 4 + r;
                const float yv = ya[r];
                als[nxt][row][j] = (_Float16)yv;     // feedback -> next x_t
                ybuf[tt][row][j] = (_Float16)yv;     // staged output
            }
        }
        __syncthreads();  // y visible before next gate GEMM; orders ybuf for flush

        if ((s & (TCH - 1)) == (TCH - 1)) {
            const int t0 = s & ~(TCH - 1);
#pragma unroll
            for (int it = 0; it < 8; ++it) {
                const int slot = it * 512 + tid;   // 0..4095
                const int pair = slot >> 2;        // (row,j): 0..1023
                const int tq   = slot & 3;
                const int row  = pair >> 6;
                const int j    = pair & 63;
                float4 v;
                v.x = (float)ybuf[tq * 4 + 0][row][j];
                v.y = (float)ybuf[tq * 4 + 1][row][j];
                v.z = (float)ybuf[tq * 4 + 2][row][j];
                v.w = (float)ybuf[tq * 4 + 3][row][j];
                *(float4*)(out + ((size_t)(b0 + row) * NOUT + j) * TOUT + t0 + tq * 4) = v;
            }
        }
    }
}

extern "C" void kernel_launch(void* const* d_in, const int* in_sizes, int n_in,
                              void* d_out, int out_size, void* d_ws, size_t ws_size,
                              hipStream_t stream) {
    (void)in_sizes; (void)n_in; (void)out_size; (void)d_ws; (void)ws_size;
    const float* x    = (const float*)d_in[0];
    const float* eWih = (const float*)d_in[1];
    const float* eWhh = (const float*)d_in[2];
    const float* eb   = (const float*)d_in[3];
    const float* dWih = (const float*)d_in[4];
    const float* dWhh = (const float*)d_in[5];
    const float* db   = (const float*)d_in[6];
    const float* oW   = (const float*)d_in[7];
    const float* ob   = (const float*)d_in[8];

    seq2seq_fused<<<BATCHN / BT, 512, 0, stream>>>(
        x, eWih, eWhh, eb, dWih, dWhh, db, oW, ob, (float*)d_out);
}